// Round 1
// baseline (102.006 us; speedup 1.0000x reference)
//
#include <hip/hip_runtime.h>
#include <math.h>

// 256-point FFT as 16x16 four-step Cooley-Tukey.
// 16 threads per batch; each thread does two register-resident FFT16s
// with an LDS transpose + W_256 twiddle in between.

#define NB 16  // batches per 256-thread block

__device__ __forceinline__ void fft16(float re[16], float im[16]) {
    // 4-bit bit-reversal permutation (swap i < rev(i))
    {
        float tr, ti;
#define SWP(a, b) tr = re[a]; re[a] = re[b]; re[b] = tr; ti = im[a]; im[a] = im[b]; im[b] = ti;
        SWP(1, 8) SWP(2, 4) SWP(3, 12) SWP(5, 10) SWP(7, 14) SWP(11, 13)
#undef SWP
    }
    // W_16^m = cos(2pi m/16) - i sin(2pi m/16)
    const float C[8] = { 1.0f,  0.92387953251f,  0.70710678119f,  0.38268343236f,
                         0.0f, -0.38268343236f, -0.70710678119f, -0.92387953251f };
    const float S[8] = { 0.0f, -0.38268343236f, -0.70710678119f, -0.92387953251f,
                        -1.0f, -0.92387953251f, -0.70710678119f, -0.38268343236f };
#pragma unroll
    for (int s = 1; s <= 4; ++s) {
        const int len = 1 << s;
        const int half = len >> 1;
        const int step = 16 >> s;  // twiddle stride into 16-entry table
#pragma unroll
        for (int i = 0; i < 16; i += len) {
#pragma unroll
            for (int j = 0; j < half; ++j) {
                const float wr = C[j * step];
                const float wi = S[j * step];
                const int p = i + j;
                const int q = i + j + half;
                const float vr = re[q] * wr - im[q] * wi;
                const float vi = re[q] * wi + im[q] * wr;
                const float ur = re[p], ui = im[p];
                re[p] = ur + vr; im[p] = ui + vi;
                re[q] = ur - vr; im[q] = ui - vi;
            }
        }
    }
}

__global__ __launch_bounds__(256) void fft256_kernel(const float* __restrict__ x,
                                                     float* __restrict__ out) {
    // +1 float padding on the inner dim -> row write & column read are
    // <=2-way bank aliased (free on CDNA4).
    __shared__ float lre[NB][16][17];
    __shared__ float lim[NB][16][17];

    const int tid = threadIdx.x;
    const int sub = tid >> 4;   // batch within block
    const int t   = tid & 15;   // n1 in phase 1, k2 in phase 2
    const int b   = blockIdx.x * NB + sub;

    const float* xr = x + (size_t)b * 512;   // x[b, 0, :]
    const float* xi = xr + 256;              // x[b, 1, :]

    float re[16], im[16];

    // Phase 1 load: thread t owns n1=t, sequence over n2 (stride 16).
    // 16 lanes x 4B = dense 64B segments -> coalesced.
#pragma unroll
    for (int i = 0; i < 16; ++i) {
        re[i] = xr[t + 16 * i];
        im[i] = xi[t + 16 * i];
    }

    fft16(re, im);  // Y[t, k2] over n2

    // Twiddle by W_256^{t*k2} and write row t (transposed read later).
#pragma unroll
    for (int k = 0; k < 16; ++k) {
        float sv, cv;
        __sincosf(-6.283185307179586f * (float)(t * k) * (1.0f / 256.0f), &sv, &cv);
        lre[sub][t][k] = re[k] * cv - im[k] * sv;
        lim[sub][t][k] = re[k] * sv + im[k] * cv;
    }

    __syncthreads();

    // Phase 2: thread t owns k2=t, gather over n1 (column read).
#pragma unroll
    for (int n = 0; n < 16; ++n) {
        re[n] = lre[sub][n][t];
        im[n] = lim[sub][n][t];
    }

    fft16(re, im);  // X[t + 16*k1] over k1

    float* outr = out + (size_t)b * 512;  // out[b, 0, :]
    float* outi = outr + 256;             // out[b, 1, :]
#pragma unroll
    for (int k = 0; k < 16; ++k) {
        outr[t + 16 * k] = re[k];
        outi[t + 16 * k] = im[k];
    }
}

extern "C" void kernel_launch(void* const* d_in, const int* in_sizes, int n_in,
                              void* d_out, int out_size, void* d_ws, size_t ws_size,
                              hipStream_t stream) {
    (void)d_ws; (void)ws_size; (void)n_in;
    const float* x = (const float*)d_in[0];
    float* out = (float*)d_out;
    const int batches = in_sizes[0] / 512;      // 131072
    const int grid = batches / NB;              // 8192 blocks
    fft256_kernel<<<grid, 256, 0, stream>>>(x, out);
}